// Round 9
// baseline (286.038 us; speedup 1.0000x reference)
//
#include <hip/hip_runtime.h>
#include <math.h>

constexpr int B = 2, C = 64, H = 80, W = 80, HW = H * W, COUT = 64;
constexpr int NPIX = B * HW;

typedef __attribute__((ext_vector_type(8))) short short8;   // 8 bf16
typedef __attribute__((ext_vector_type(4))) float f32x4;
typedef __attribute__((ext_vector_type(2))) float f32x2;
typedef __attribute__((ext_vector_type(4))) int i32x4;

__device__ inline ushort f2bf(float f) {
  unsigned u = __float_as_uint(f);
  unsigned r = u + 0x7fff + ((u >> 16) & 1);   // RNE
  return (ushort)(r >> 16);
}

__device__ inline f32x2 unpack_bf2(unsigned u) {
  f32x2 r;
  r.x = __uint_as_float(u << 16);
  r.y = __uint_as_float(u & 0xffff0000u);
  return r;
}

// bilinear-combine 2 bf16 channels x 4 corners, repack to 2 bf16 (1 v_perm)
__device__ inline unsigned bilin_pack(unsigned a, unsigned b, unsigned c,
                                      unsigned d, f32x2 c00, f32x2 c01,
                                      f32x2 c10, f32x2 c11) {
  f32x2 p = unpack_bf2(a) * c00;
  p += unpack_bf2(b) * c01;
  p += unpack_bf2(c) * c10;
  p += unpack_bf2(d) * c11;
  unsigned lo = __float_as_uint(p.x) + 0x8000u;
  unsigned hi = __float_as_uint(p.y) + 0x8000u;
  return __builtin_amdgcn_perm(hi, lo, 0x07060302);
}

// ---------------------------------------------------------------------------
// Weight prep body (grid-stride over this branch's swizzled tables).
// ---------------------------------------------------------------------------
template <int K, int NT>
__device__ void prep_body(int pb, int nblk, const float* __restrict__ w_off,
                          const float* __restrict__ b_off,
                          const float* __restrict__ w_mask,
                          const float* __restrict__ b_mask,
                          const float* __restrict__ w_dcn,
                          ushort* __restrict__ wtbs, float* __restrict__ bcomb,
                          ushort* __restrict__ wdts) {
  constexpr int KK = K * K, C3 = 3 * KK;
  const int n1 = KK * 2 * NT * 512;
  const int n2 = C3;
  const int n3 = KK * 2 * 4 * 512;
  const int total = n1 + n2 + n3;
  for (int i = pb * 256 + threadIdx.x; i < total; i += nblk * 256) {
    if (i < n1) {
      int e = i & 7, l = (i >> 3) & 63;
      int blk512 = i >> 9;
      int nt = blk512 % NT, th = blk512 / NT;
      int half = th & 1, t = th >> 1;
      int n = nt * 16 + (l & 15);
      int ci = half * 32 + (l >> 4) * 8 + e;
      float v = 0.f;
      if (n < 2 * KK) v = w_off[(n * C + ci) * KK + t];
      else if (n < C3) v = w_mask[((n - 2 * KK) * C + ci) * KK + t];
      wtbs[i] = f2bf(v);
    } else if (i < n1 + n2) {
      int co = i - n1;
      bcomb[co] = (co < 2 * KK) ? b_off[co] : b_mask[co - 2 * KK];
    } else {
      int j = i - n1 - n2;
      int e = j & 7, l = (j >> 3) & 63;
      int blk512 = j >> 9;
      int jt = blk512 & 3, th = blk512 >> 2;
      int half = th & 1, t = th >> 1;
      int co = jt * 16 + (l & 15);
      int ci = half * 32 + (l >> 4) * 8 + e;
      wdts[j] = f2bf(w_dcn[(co * C + ci) * KK + t]);
    }
  }
}

// ---------------------------------------------------------------------------
// setup_all: blocks 0..199 transpose NCHW->NHWC bf16 (+zero row); rest prep.
// ---------------------------------------------------------------------------
__global__ __launch_bounds__(256) void setup_all(
    const float* __restrict__ x, ushort* __restrict__ xhb,
    const float* __restrict__ w_off3, const float* __restrict__ b_off3,
    const float* __restrict__ w_mask3, const float* __restrict__ b_mask3,
    const float* __restrict__ w_dcn3, ushort* __restrict__ wtbs3,
    float* __restrict__ bc3, ushort* __restrict__ wdts3,
    const float* __restrict__ w_off5, const float* __restrict__ b_off5,
    const float* __restrict__ w_mask5, const float* __restrict__ b_mask5,
    const float* __restrict__ w_dcn5, ushort* __restrict__ wtbs5,
    float* __restrict__ bc5, ushort* __restrict__ wdts5,
    const float* __restrict__ w_off7, const float* __restrict__ b_off7,
    const float* __restrict__ w_mask7, const float* __restrict__ b_mask7,
    const float* __restrict__ w_dcn7, ushort* __restrict__ wtbs7,
    float* __restrict__ bc7, ushort* __restrict__ wdts7) {
  __shared__ float tile[64][65];
  int blk = blockIdx.x;
  if (blk < 200) {
    int b = blk / (HW / 64);
    int p0 = (blk % (HW / 64)) * 64;
    int lane = threadIdx.x & 63, row = threadIdx.x >> 6;
    if (blk == 0 && threadIdx.x < 64)
      xhb[(size_t)NPIX * C + threadIdx.x] = 0;   // zero row for OOB loads
#pragma unroll
    for (int it = 0; it < 16; ++it) {
      int ci = it * 4 + row;
      tile[ci][lane] = x[(size_t)(b * C + ci) * HW + p0 + lane];
    }
    __syncthreads();
#pragma unroll
    for (int it = 0; it < 16; ++it) {
      int pl = it * 4 + row;
      xhb[((size_t)b * HW + p0 + pl) * C + lane] = f2bf(tile[lane][pl]);
    }
  } else {
    int pb = blk - 200;
    prep_body<7, 10>(pb, 256, w_off7, b_off7, w_mask7, b_mask7, w_dcn7, wtbs7,
                     bc7, wdts7);
    prep_body<5, 6>(pb, 256, w_off5, b_off5, w_mask5, b_mask5, w_dcn5, wtbs5,
                    bc5, wdts5);
    prep_body<3, 2>(pb, 256, w_off3, b_off3, w_mask3, b_mask3, w_dcn3, wtbs3,
                    bc3, wdts3);
  }
}

// ---------------------------------------------------------------------------
// Conv body: implicit-im2col bf16 MFMA GEMM, straight-line K-loop, OOB via
// zero-row redirect. Plain code: latency hidden by TLP, not forced ILP.
// ---------------------------------------------------------------------------
template <int K, int NT, int NTA, int MB>
__device__ __forceinline__ void conv_body(int blk,
                                          const ushort* __restrict__ xhb,
                                          const ushort* __restrict__ wtbs,
                                          const float* __restrict__ bcomb,
                                          float* __restrict__ convout) {
  constexpr int PAD = K / 2, KK = K * K, C3 = 3 * KK;
  constexpr int NG = NT / NTA;
  static_assert(NG * NTA == NT, "exact n-split");
  const int ZPIX = NPIX;                   // zero-row pixel index
  int tid = threadIdx.x;
  int wid = blk * 4 + (tid >> 6);
  int mt = wid / NG;
  int g = wid % NG;
  int j0 = g * NTA;
  int l = tid & 63;
  int lm = l & 15, lk = l >> 4;
  int m0 = mt * (16 * MB);
  int b = m0 / HW;
  int y[MB], x0[MB];
#pragma unroll
  for (int i = 0; i < MB; ++i) {
    int rem = (m0 + 16 * i) % HW;
    y[i] = rem / W;
    x0[i] = rem % W;                       // 16 | W -> tile stays in one row
  }
  f32x4 acc[MB][NTA];
#pragma unroll
  for (int i = 0; i < MB; ++i)
#pragma unroll
    for (int j = 0; j < NTA; ++j) acc[i][j] = f32x4{0.f, 0.f, 0.f, 0.f};

#pragma unroll
  for (int ky = 0; ky < K; ++ky) {
#pragma unroll
    for (int kx = 0; kx < K; ++kx) {
      int t = ky * K + kx;
      const ushort* fbase = wtbs + (size_t)(t * 2) * NT * 512 + l * 8;
      short8 a0[MB], a1[MB];
#pragma unroll
      for (int i = 0; i < MB; ++i) {
        int yy = y[i] + ky - PAD;
        int xx = x0[i] + lm + kx - PAD;
        bool v = ((unsigned)yy < (unsigned)H) && ((unsigned)xx < (unsigned)W);
        int pidx = b * HW + yy * W + xx;
        const ushort* ap = xhb + (size_t)(v ? pidx : ZPIX) * C + lk * 8;
        a0[i] = *(const short8*)ap;
        a1[i] = *(const short8*)(ap + 32);
      }
      short8 b0[NTA], b1[NTA];
#pragma unroll
      for (int jj = 0; jj < NTA; ++jj) {
        b0[jj] = *(const short8*)(fbase + (size_t)(j0 + jj) * 512);
        b1[jj] = *(const short8*)(fbase + (size_t)(NT + j0 + jj) * 512);
      }
#pragma unroll
      for (int jj = 0; jj < NTA; ++jj)
#pragma unroll
        for (int i = 0; i < MB; ++i)
          acc[i][jj] = __builtin_amdgcn_mfma_f32_16x16x32_bf16(a0[i], b0[jj],
                                                              acc[i][jj], 0, 0, 0);
#pragma unroll
      for (int jj = 0; jj < NTA; ++jj)
#pragma unroll
        for (int i = 0; i < MB; ++i)
          acc[i][jj] = __builtin_amdgcn_mfma_f32_16x16x32_bf16(a1[i], b1[jj],
                                                              acc[i][jj], 0, 0, 0);
    }
  }

  // Epilogue. D mapping: col(n)=lm, row(m)=lk*4+r.
#pragma unroll
  for (int i = 0; i < MB; ++i) {
#pragma unroll
    for (int jj = 0; jj < NTA; ++jj) {
      int co = (j0 + jj) * 16 + lm;
      if (co >= C3) continue;              // only k=5 padding hits this
      float bs = bcomb[co];
      bool isoff = co < 2 * KK;
      int tp = co >> 1;
#pragma unroll
      for (int r = 0; r < 4; ++r) {
        int xr = x0[i] + lk * 4 + r;
        int pix = m0 + 16 * i + lk * 4 + r;
        float v = acc[i][jj][r] + bs;
        if (isoff) {
          v += (co & 1) ? (float)(xr - PAD + tp % K)    // px
                        : (float)(y[i] - PAD + tp / K); // py
        } else {
          v = 1.f / (1.f + expf(-v));
        }
        convout[(size_t)pix * C3 + co] = v;
      }
    }
  }
}

__global__ __launch_bounds__(256, 4) void conv_all(
    const ushort* __restrict__ xhb,
    const ushort* __restrict__ wtbs7, const float* __restrict__ bc7, float* __restrict__ co7,
    const ushort* __restrict__ wtbs5, const float* __restrict__ bc5, float* __restrict__ co5,
    const ushort* __restrict__ wtbs3, const float* __restrict__ bc3, float* __restrict__ co3) {
  int blk = blockIdx.x;
  if (blk < 500) conv_body<7, 10, 2, 2>(blk, xhb, wtbs7, bc7, co7);           // NG=5
  else if (blk < 700) conv_body<5, 6, 3, 2>(blk - 500, xhb, wtbs5, bc5, co5); // NG=2
  else conv_body<3, 2, 2, 2>(blk - 700, xhb, wtbs3, bc3, co3);                // NG=1
}

// ---------------------------------------------------------------------------
// meta_all: per (tap, pixel) build mask-folded bilinear coeffs + 4 clamped
// byte offsets (within batch) into a GLOBAL t-major table, 8 dwords/entry.
// Dummy taps (t >= KK) get zero coeffs / offset 0.
// ---------------------------------------------------------------------------
template <int K>
__device__ void meta_body(int gid, int stride, const float* __restrict__ convout,
                          float* __restrict__ meta) {
  constexpr int KK = K * K, C3 = 3 * KK;
  constexpr int TPW = (KK + 3) / 4, TAPS4 = TPW * 4;
  const int total = TAPS4 * NPIX;
  for (int idx = gid; idx < total; idx += stride) {
    int t = idx / NPIX;
    int pix = idx - t * NPIX;
    bool tv = t < KK;
    int ts = tv ? t : 0;
    const float* cp = convout + (size_t)pix * C3;
    float py = cp[2 * ts], px = cp[2 * ts + 1];
    float m = tv ? cp[2 * KK + ts] : 0.f;
    float fy = floorf(py), fx = floorf(px);
    float wy1 = py - fy, wx1 = px - fx;
    float wy0 = 1.f - wy1, wx0 = 1.f - wx1;
    int y0 = (int)fy, x0 = (int)fx;
    int y1 = y0 + 1, x1 = x0 + 1;
    bool vy0 = (unsigned)y0 < (unsigned)H, vy1 = (unsigned)y1 < (unsigned)H;
    bool vx0 = (unsigned)x0 < (unsigned)W, vx1 = (unsigned)x1 < (unsigned)W;
    f32x4 cf;
    cf.x = m * wy0 * wx0 * ((vy0 & vx0) ? 1.f : 0.f);
    cf.y = m * wy0 * wx1 * ((vy0 & vx1) ? 1.f : 0.f);
    cf.z = m * wy1 * wx0 * ((vy1 & vx0) ? 1.f : 0.f);
    cf.w = m * wy1 * wx1 * ((vy1 & vx1) ? 1.f : 0.f);
    int y0c = min(max(y0, 0), H - 1), y1c = min(max(y1, 0), H - 1);
    int x0c = min(max(x0, 0), W - 1), x1c = min(max(x1, 0), W - 1);
    i32x4 of;
    of.x = (y0c * W + x0c) * C * 2;        // byte offsets within batch slab
    of.y = (y0c * W + x1c) * C * 2;
    of.z = (y1c * W + x0c) * C * 2;
    of.w = (y1c * W + x1c) * C * 2;
    float* mp = meta + (size_t)idx * 8;
    *(f32x4*)mp = cf;
    *(i32x4*)(mp + 4) = of;
  }
}

__global__ __launch_bounds__(256) void meta_all(
    const float* __restrict__ co7, float* __restrict__ m7,
    const float* __restrict__ co5, float* __restrict__ m5,
    const float* __restrict__ co3, float* __restrict__ m3) {
  int gid = blockIdx.x * 256 + threadIdx.x;
  int stride = gridDim.x * 256;
  meta_body<7>(gid, stride, co7, m7);
  meta_body<5>(gid, stride, co5, m5);
  meta_body<3>(gid, stride, co3, m3);
}

// ---------------------------------------------------------------------------
// DCN body v2: zero in-loop LDS. Per tap: 2 coalesced meta loads (global,
// t-major: wave reads 512B contiguous) + 8 gathers + pack + 8 MFMA.
// Block = 16 pixels, 4 waves K-split, LDS only for the final reduction.
// ---------------------------------------------------------------------------
template <int K>
__device__ __forceinline__ void dcn_body(int blk, const ushort* __restrict__ xhb,
                                         const float* __restrict__ meta,
                                         const ushort* __restrict__ wdts,
                                         float* __restrict__ out, int br_off,
                                         float (*s_red)[16][65]) {
  constexpr int KK = K * K;
  constexpr int TPW = (KK + 3) / 4;
  int tid = threadIdx.x, w = tid >> 6, l = tid & 63;
  int lm = l & 15, lk = l >> 4;
  int m0 = blk * 16;
  int b = m0 / HW;
  const char* xc = (const char*)(xhb + (size_t)b * HW * C);
  int cb = lk * 16;                        // this lane's channel byte offset
  f32x4 acc[4];
#pragma unroll
  for (int j = 0; j < 4; ++j) acc[j] = f32x4{0.f, 0.f, 0.f, 0.f};

#pragma unroll
  for (int tt = 0; tt < TPW; ++tt) {
    int t = w * TPW + tt;                  // wave-uniform
    int ts = (t < KK) ? t : 0;             // clamp for B-table address
    const float* mp = meta + ((size_t)t * NPIX + m0 + lm) * 8;
    f32x4 cf = *(const f32x4*)mp;
    i32x4 of = *(const i32x4*)(mp + 4);
    uint4 u00a = *(const uint4*)(xc + of.x + cb);
    uint4 u00b = *(const uint4*)(xc + of.x + cb + 64);
    uint4 u01a = *(const uint4*)(xc + of.y + cb);
    uint4 u01b = *(const uint4*)(xc + of.y + cb + 64);
    uint4 u10a = *(const uint4*)(xc + of.z + cb);
    uint4 u10b = *(const uint4*)(xc + of.z + cb + 64);
    uint4 u11a = *(const uint4*)(xc + of.w + cb);
    uint4 u11b = *(const uint4*)(xc + of.w + cb + 64);
    f32x2 c00 = {cf.x, cf.x}, c01 = {cf.y, cf.y};
    f32x2 c10 = {cf.z, cf.z}, c11 = {cf.w, cf.w};
    uint4 apa, apb;
    apa.x = bilin_pack(u00a.x, u01a.x, u10a.x, u11a.x, c00, c01, c10, c11);
    apa.y = bilin_pack(u00a.y, u01a.y, u10a.y, u11a.y, c00, c01, c10, c11);
    apa.z = bilin_pack(u00a.z, u01a.z, u10a.z, u11a.z, c00, c01, c10, c11);
    apa.w = bilin_pack(u00a.w, u01a.w, u10a.w, u11a.w, c00, c01, c10, c11);
    apb.x = bilin_pack(u00b.x, u01b.x, u10b.x, u11b.x, c00, c01, c10, c11);
    apb.y = bilin_pack(u00b.y, u01b.y, u10b.y, u11b.y, c00, c01, c10, c11);
    apb.z = bilin_pack(u00b.z, u01b.z, u10b.z, u11b.z, c00, c01, c10, c11);
    apb.w = bilin_pack(u00b.w, u01b.w, u10b.w, u11b.w, c00, c01, c10, c11);
    short8 aa = *(short8*)&apa;
    short8 ab = *(short8*)&apb;
    const ushort* fb0 = wdts + (size_t)((ts * 2 + 0) * 4) * 512 + l * 8;
    const ushort* fb1 = wdts + (size_t)((ts * 2 + 1) * 4) * 512 + l * 8;
#pragma unroll
    for (int j = 0; j < 4; ++j) {
      short8 bf = *(const short8*)(fb0 + j * 512);
      acc[j] = __builtin_amdgcn_mfma_f32_16x16x32_bf16(aa, bf, acc[j], 0, 0, 0);
    }
#pragma unroll
    for (int j = 0; j < 4; ++j) {
      short8 bf = *(const short8*)(fb1 + j * 512);
      acc[j] = __builtin_amdgcn_mfma_f32_16x16x32_bf16(ab, bf, acc[j], 0, 0, 0);
    }
  }

  // K-split reduction across the 4 waves. D map: col=lm(co), row=lk*4+r(pixel).
#pragma unroll
  for (int j = 0; j < 4; ++j)
#pragma unroll
    for (int r = 0; r < 4; ++r)
      s_red[w][lk * 4 + r][j * 16 + lm] = acc[j][r];
  __syncthreads();
  int rem0 = m0 - b * HW;
#pragma unroll
  for (int i = 0; i < 4; ++i) {
    int idx = i * 256 + tid;
    int mrow = idx & 15, co = idx >> 4;
    float v = s_red[0][mrow][co] + s_red[1][mrow][co] +
              s_red[2][mrow][co] + s_red[3][mrow][co];
    out[(size_t)(b * (3 * COUT) + br_off + co) * HW + rem0 + mrow] = v;
  }
}

__global__ __launch_bounds__(256, 6) void dcn_all(
    const ushort* __restrict__ xhb,
    const float* __restrict__ m7, const ushort* __restrict__ wdts7,
    const float* __restrict__ m5, const ushort* __restrict__ wdts5,
    const float* __restrict__ m3, const ushort* __restrict__ wdts3,
    float* __restrict__ out) {
  __shared__ float s_red[4][16][65];       // 16.6 KB
  int blk = blockIdx.x;
  if (blk < 800) dcn_body<7>(blk, xhb, m7, wdts7, out, 128, s_red);
  else if (blk < 1600) dcn_body<5>(blk - 800, xhb, m5, wdts5, out, 64, s_red);
  else dcn_body<3>(blk - 1600, xhb, m3, wdts3, out, 0, s_red);
}

// ---------------------------------------------------------------------------
// Launch
// ---------------------------------------------------------------------------
extern "C" void kernel_launch(void* const* d_in, const int* in_sizes, int n_in,
                              void* d_out, int out_size, void* d_ws,
                              size_t ws_size, hipStream_t stream) {
  const float* x = (const float*)d_in[0];
  const float* w_off3 = (const float*)d_in[1];
  const float* b_off3 = (const float*)d_in[2];
  const float* w_mask3 = (const float*)d_in[3];
  const float* b_mask3 = (const float*)d_in[4];
  const float* w_dcn3 = (const float*)d_in[5];
  const float* w_off5 = (const float*)d_in[6];
  const float* b_off5 = (const float*)d_in[7];
  const float* w_mask5 = (const float*)d_in[8];
  const float* b_mask5 = (const float*)d_in[9];
  const float* w_dcn5 = (const float*)d_in[10];
  const float* w_off7 = (const float*)d_in[11];
  const float* b_off7 = (const float*)d_in[12];
  const float* w_mask7 = (const float*)d_in[13];
  const float* b_mask7 = (const float*)d_in[14];
  const float* w_dcn7 = (const float*)d_in[15];
  float* out = (float*)d_out;
  float* ws = (float*)d_ws;

  // Workspace layout (float units, 16B aligned)
  size_t off = 0;
  auto alloc = [&](size_t n) {
    size_t p = off;
    off += (n + 3) & ~(size_t)3;
    return ws + p;
  };
  ushort* xhb = (ushort*)alloc((size_t)NPIX * C / 2 + 64);  // +zero row
  float* co3 = alloc((size_t)NPIX * 27);
  float* co5 = alloc((size_t)NPIX * 75);
  float* co7 = alloc((size_t)NPIX * 147);
  ushort* wtbs3 = (ushort*)alloc(9 * 2 * 2 * 512 / 2);
  ushort* wtbs5 = (ushort*)alloc(25 * 2 * 6 * 512 / 2);
  ushort* wtbs7 = (ushort*)alloc(49 * 2 * 10 * 512 / 2);
  float* bc3 = alloc(27);
  float* bc5 = alloc(75);
  float* bc7 = alloc(147);
  ushort* wdts3 = (ushort*)alloc(9 * 2 * 4 * 512 / 2);
  ushort* wdts5 = (ushort*)alloc(25 * 2 * 4 * 512 / 2);
  ushort* wdts7 = (ushort*)alloc(49 * 2 * 4 * 512 / 2);
  float* m7 = alloc((size_t)52 * NPIX * 8);   // 21.3 MB
  float* m5 = alloc((size_t)28 * NPIX * 8);   // 11.5 MB
  float* m3 = alloc((size_t)12 * NPIX * 8);   //  4.9 MB

  // 1) transpose + all weight prep (one launch)
  setup_all<<<456, 256, 0, stream>>>(
      x, xhb,
      w_off3, b_off3, w_mask3, b_mask3, w_dcn3, wtbs3, bc3, wdts3,
      w_off5, b_off5, w_mask5, b_mask5, w_dcn5, wtbs5, bc5, wdts5,
      w_off7, b_off7, w_mask7, b_mask7, w_dcn7, wtbs7, bc7, wdts7);

  // 2) all offset+mask convs (one launch; k=7 500 blocks, k=5 200, k=3 100)
  conv_all<<<800, 256, 0, stream>>>(xhb, wtbs7, bc7, co7, wtbs5, bc5, co5,
                                    wtbs3, bc3, co3);

  // 3) sampling metadata (coeffs + clamped offsets) to global tables
  meta_all<<<1280, 256, 0, stream>>>(co7, m7, co5, m5, co3, m3);

  // 4) all fused deformable sampling + einsum (one launch, k=7 first)
  dcn_all<<<2400, 256, 0, stream>>>(xhb, m7, wdts7, m5, wdts5, m3, wdts3,
                                    out);
}

// Round 10
// 271.773 us; speedup vs baseline: 1.0525x; 1.0525x over previous
//
#include <hip/hip_runtime.h>
#include <math.h>

constexpr int B = 2, C = 64, H = 80, W = 80, HW = H * W, COUT = 64;
constexpr int NPIX = B * HW;

typedef __attribute__((ext_vector_type(8))) short short8;   // 8 bf16
typedef __attribute__((ext_vector_type(4))) float f32x4;
typedef __attribute__((ext_vector_type(2))) float f32x2;

__device__ inline ushort f2bf(float f) {
  unsigned u = __float_as_uint(f);
  unsigned r = u + 0x7fff + ((u >> 16) & 1);   // RNE
  return (ushort)(r >> 16);
}

__device__ inline f32x2 unpack_bf2(unsigned u) {
  f32x2 r;
  r.x = __uint_as_float(u << 16);
  r.y = __uint_as_float(u & 0xffff0000u);
  return r;
}

// bilinear-combine 2 bf16 channels x 4 corners, repack to 2 bf16 (1 v_perm)
__device__ inline unsigned bilin_pack(unsigned a, unsigned b, unsigned c,
                                      unsigned d, f32x2 c00, f32x2 c01,
                                      f32x2 c10, f32x2 c11) {
  f32x2 p = unpack_bf2(a) * c00;
  p += unpack_bf2(b) * c01;
  p += unpack_bf2(c) * c10;
  p += unpack_bf2(d) * c11;
  unsigned lo = __float_as_uint(p.x) + 0x8000u;
  unsigned hi = __float_as_uint(p.y) + 0x8000u;
  return __builtin_amdgcn_perm(hi, lo, 0x07060302);
}

// ---------------------------------------------------------------------------
// Weight prep body (grid-stride over this branch's swizzled tables).
// ---------------------------------------------------------------------------
template <int K, int NT>
__device__ void prep_body(int pb, int nblk, const float* __restrict__ w_off,
                          const float* __restrict__ b_off,
                          const float* __restrict__ w_mask,
                          const float* __restrict__ b_mask,
                          const float* __restrict__ w_dcn,
                          ushort* __restrict__ wtbs, float* __restrict__ bcomb,
                          ushort* __restrict__ wdts) {
  constexpr int KK = K * K, C3 = 3 * KK;
  const int n1 = KK * 2 * NT * 512;
  const int n2 = C3;
  const int n3 = KK * 2 * 4 * 512;
  const int total = n1 + n2 + n3;
  for (int i = pb * 256 + threadIdx.x; i < total; i += nblk * 256) {
    if (i < n1) {
      int e = i & 7, l = (i >> 3) & 63;
      int blk512 = i >> 9;
      int nt = blk512 % NT, th = blk512 / NT;
      int half = th & 1, t = th >> 1;
      int n = nt * 16 + (l & 15);
      int ci = half * 32 + (l >> 4) * 8 + e;
      float v = 0.f;
      if (n < 2 * KK) v = w_off[(n * C + ci) * KK + t];
      else if (n < C3) v = w_mask[((n - 2 * KK) * C + ci) * KK + t];
      wtbs[i] = f2bf(v);
    } else if (i < n1 + n2) {
      int co = i - n1;
      bcomb[co] = (co < 2 * KK) ? b_off[co] : b_mask[co - 2 * KK];
    } else {
      int j = i - n1 - n2;
      int e = j & 7, l = (j >> 3) & 63;
      int blk512 = j >> 9;
      int jt = blk512 & 3, th = blk512 >> 2;
      int half = th & 1, t = th >> 1;
      int co = jt * 16 + (l & 15);
      int ci = half * 32 + (l >> 4) * 8 + e;
      wdts[j] = f2bf(w_dcn[(co * C + ci) * KK + t]);
    }
  }
}

// ---------------------------------------------------------------------------
// setup_all: blocks 0..199 transpose NCHW->NHWC bf16 (+zero row); rest prep.
// ---------------------------------------------------------------------------
__global__ __launch_bounds__(256) void setup_all(
    const float* __restrict__ x, ushort* __restrict__ xhb,
    const float* __restrict__ w_off3, const float* __restrict__ b_off3,
    const float* __restrict__ w_mask3, const float* __restrict__ b_mask3,
    const float* __restrict__ w_dcn3, ushort* __restrict__ wtbs3,
    float* __restrict__ bc3, ushort* __restrict__ wdts3,
    const float* __restrict__ w_off5, const float* __restrict__ b_off5,
    const float* __restrict__ w_mask5, const float* __restrict__ b_mask5,
    const float* __restrict__ w_dcn5, ushort* __restrict__ wtbs5,
    float* __restrict__ bc5, ushort* __restrict__ wdts5,
    const float* __restrict__ w_off7, const float* __restrict__ b_off7,
    const float* __restrict__ w_mask7, const float* __restrict__ b_mask7,
    const float* __restrict__ w_dcn7, ushort* __restrict__ wtbs7,
    float* __restrict__ bc7, ushort* __restrict__ wdts7) {
  __shared__ float tile[64][65];
  int blk = blockIdx.x;
  if (blk < 200) {
    int b = blk / (HW / 64);
    int p0 = (blk % (HW / 64)) * 64;
    int lane = threadIdx.x & 63, row = threadIdx.x >> 6;
    if (blk == 0 && threadIdx.x < 64)
      xhb[(size_t)NPIX * C + threadIdx.x] = 0;   // zero row for OOB loads
#pragma unroll
    for (int it = 0; it < 16; ++it) {
      int ci = it * 4 + row;
      tile[ci][lane] = x[(size_t)(b * C + ci) * HW + p0 + lane];
    }
    __syncthreads();
#pragma unroll
    for (int it = 0; it < 16; ++it) {
      int pl = it * 4 + row;
      xhb[((size_t)b * HW + p0 + pl) * C + lane] = f2bf(tile[lane][pl]);
    }
  } else {
    int pb = blk - 200;
    prep_body<7, 10>(pb, 256, w_off7, b_off7, w_mask7, b_mask7, w_dcn7, wtbs7,
                     bc7, wdts7);
    prep_body<5, 6>(pb, 256, w_off5, b_off5, w_mask5, b_mask5, w_dcn5, wtbs5,
                    bc5, wdts5);
    prep_body<3, 2>(pb, 256, w_off3, b_off3, w_mask3, b_mask3, w_dcn3, wtbs3,
                    bc3, wdts3);
  }
}

// ---------------------------------------------------------------------------
// Conv body: implicit-im2col bf16 MFMA GEMM, straight-line K-loop, OOB via
// zero-row redirect. MB=1: minimum work per wave, maximum wave count (TLP).
// ---------------------------------------------------------------------------
template <int K, int NT, int NTA, int MB>
__device__ __forceinline__ void conv_body(int blk,
                                          const ushort* __restrict__ xhb,
                                          const ushort* __restrict__ wtbs,
                                          const float* __restrict__ bcomb,
                                          float* __restrict__ convout) {
  constexpr int PAD = K / 2, KK = K * K, C3 = 3 * KK;
  constexpr int NG = NT / NTA;
  static_assert(NG * NTA == NT, "exact n-split");
  const int ZPIX = NPIX;                   // zero-row pixel index
  int tid = threadIdx.x;
  int wid = blk * 4 + (tid >> 6);
  int mt = wid / NG;
  int g = wid % NG;
  int j0 = g * NTA;
  int l = tid & 63;
  int lm = l & 15, lk = l >> 4;
  int m0 = mt * (16 * MB);
  int b = m0 / HW;
  int y[MB], x0[MB];
#pragma unroll
  for (int i = 0; i < MB; ++i) {
    int rem = (m0 + 16 * i) % HW;
    y[i] = rem / W;
    x0[i] = rem % W;                       // 16 | W -> tile stays in one row
  }
  f32x4 acc[MB][NTA];
#pragma unroll
  for (int i = 0; i < MB; ++i)
#pragma unroll
    for (int j = 0; j < NTA; ++j) acc[i][j] = f32x4{0.f, 0.f, 0.f, 0.f};

#pragma unroll
  for (int ky = 0; ky < K; ++ky) {
#pragma unroll
    for (int kx = 0; kx < K; ++kx) {
      int t = ky * K + kx;
      const ushort* fbase = wtbs + (size_t)(t * 2) * NT * 512 + l * 8;
      short8 a0[MB], a1[MB];
#pragma unroll
      for (int i = 0; i < MB; ++i) {
        int yy = y[i] + ky - PAD;
        int xx = x0[i] + lm + kx - PAD;
        bool v = ((unsigned)yy < (unsigned)H) && ((unsigned)xx < (unsigned)W);
        int pidx = b * HW + yy * W + xx;
        const ushort* ap = xhb + (size_t)(v ? pidx : ZPIX) * C + lk * 8;
        a0[i] = *(const short8*)ap;
        a1[i] = *(const short8*)(ap + 32);
      }
      short8 b0[NTA], b1[NTA];
#pragma unroll
      for (int jj = 0; jj < NTA; ++jj) {
        b0[jj] = *(const short8*)(fbase + (size_t)(j0 + jj) * 512);
        b1[jj] = *(const short8*)(fbase + (size_t)(NT + j0 + jj) * 512);
      }
#pragma unroll
      for (int jj = 0; jj < NTA; ++jj)
#pragma unroll
        for (int i = 0; i < MB; ++i)
          acc[i][jj] = __builtin_amdgcn_mfma_f32_16x16x32_bf16(a0[i], b0[jj],
                                                              acc[i][jj], 0, 0, 0);
#pragma unroll
      for (int jj = 0; jj < NTA; ++jj)
#pragma unroll
        for (int i = 0; i < MB; ++i)
          acc[i][jj] = __builtin_amdgcn_mfma_f32_16x16x32_bf16(a1[i], b1[jj],
                                                              acc[i][jj], 0, 0, 0);
    }
  }

  // Epilogue. D mapping: col(n)=lm, row(m)=lk*4+r.
#pragma unroll
  for (int i = 0; i < MB; ++i) {
#pragma unroll
    for (int jj = 0; jj < NTA; ++jj) {
      int co = (j0 + jj) * 16 + lm;
      if (co >= C3) continue;              // only k=5 padding hits this
      float bs = bcomb[co];
      bool isoff = co < 2 * KK;
      int tp = co >> 1;
#pragma unroll
      for (int r = 0; r < 4; ++r) {
        int xr = x0[i] + lk * 4 + r;
        int pix = m0 + 16 * i + lk * 4 + r;
        float v = acc[i][jj][r] + bs;
        if (isoff) {
          v += (co & 1) ? (float)(xr - PAD + tp % K)    // px
                        : (float)(y[i] - PAD + tp / K); // py
        } else {
          v = 1.f / (1.f + expf(-v));
        }
        convout[(size_t)pix * C3 + co] = v;
      }
    }
  }
}

__global__ __launch_bounds__(256, 6) void conv_all(
    const ushort* __restrict__ xhb,
    const ushort* __restrict__ wtbs7, const float* __restrict__ bc7, float* __restrict__ co7,
    const ushort* __restrict__ wtbs5, const float* __restrict__ bc5, float* __restrict__ co5,
    const ushort* __restrict__ wtbs3, const float* __restrict__ bc3, float* __restrict__ co3) {
  int blk = blockIdx.x;
  if (blk < 1000) conv_body<7, 10, 2, 1>(blk, xhb, wtbs7, bc7, co7);            // NG=5
  else if (blk < 1400) conv_body<5, 6, 3, 1>(blk - 1000, xhb, wtbs5, bc5, co5); // NG=2
  else conv_body<3, 2, 2, 1>(blk - 1400, xhb, wtbs3, bc3, co3);                 // NG=1
}

// ---------------------------------------------------------------------------
// DCN body: fused deformable-sampling + einsum as implicit-A bf16 MFMA GEMM.
// Plain per-tap chain (meta computed inline from LDS-staged convout); latency
// hidden purely by TLP (launch_bounds(256,8), VGPR<=64, 32 waves/CU).
// ---------------------------------------------------------------------------
template <int K>
__device__ __forceinline__ void dcn_body(int blk, const ushort* __restrict__ xhb,
                                         const float* __restrict__ convout,
                                         const ushort* __restrict__ wdts,
                                         float* __restrict__ out, int br_off,
                                         float* smem) {
  constexpr int KK = K * K, C3 = 3 * KK;
  constexpr int TPW = (KK + 3) / 4;
  float* s_cv = smem;                                 // 16*C3 floats
  float (*s_red)[16][65] = (float (*)[16][65])smem;   // reused after loop
  int tid = threadIdx.x, w = tid >> 6, l = tid & 63;
  int lm = l & 15, lk = l >> 4;
  int m0 = blk * 16;
  int b = m0 / HW;
  const ushort* xb = xhb + (size_t)b * HW * C;
  for (int idx = tid; idx < 16 * C3; idx += 256)
    s_cv[idx] = convout[(size_t)m0 * C3 + idx];
  __syncthreads();
  const float* cp = s_cv + lm * C3;
  f32x4 acc[4];
#pragma unroll
  for (int j = 0; j < 4; ++j) acc[j] = f32x4{0.f, 0.f, 0.f, 0.f};

#pragma unroll
  for (int tt = 0; tt < TPW; ++tt) {
    int t = w * TPW + tt;                  // wave-uniform, may exceed KK
    bool tv = t < KK;
    int ts = tv ? t : 0;
    float py = cp[2 * ts], px = cp[2 * ts + 1];
    float m = tv ? cp[2 * KK + ts] : 0.f;  // dummy taps contribute exactly 0
    float fy = floorf(py), fx = floorf(px);
    float wy1 = py - fy, wx1 = px - fx;
    float wy0 = 1.f - wy1, wx0 = 1.f - wx1;
    int y0 = (int)fy, x0 = (int)fx;
    int y1 = y0 + 1, x1 = x0 + 1;
    bool vy0 = (unsigned)y0 < (unsigned)H, vy1 = (unsigned)y1 < (unsigned)H;
    bool vx0 = (unsigned)x0 < (unsigned)W, vx1 = (unsigned)x1 < (unsigned)W;
    float c00 = m * wy0 * wx0 * ((vy0 & vx0) ? 1.f : 0.f);
    float c01 = m * wy0 * wx1 * ((vy0 & vx1) ? 1.f : 0.f);
    float c10 = m * wy1 * wx0 * ((vy1 & vx0) ? 1.f : 0.f);
    float c11 = m * wy1 * wx1 * ((vy1 & vx1) ? 1.f : 0.f);
    f32x2 C00 = {c00, c00}, C01 = {c01, c01}, C10 = {c10, c10}, C11 = {c11, c11};
    int y0c = min(max(y0, 0), H - 1), y1c = min(max(y1, 0), H - 1);
    int x0c = min(max(x0, 0), W - 1), x1c = min(max(x1, 0), W - 1);
    int i00 = (y0c * W + x0c) * C + lk * 8, i01 = (y0c * W + x1c) * C + lk * 8;
    int i10 = (y1c * W + x0c) * C + lk * 8, i11 = (y1c * W + x1c) * C + lk * 8;
#pragma unroll
    for (int half = 0; half < 2; ++half) {
      int cb = half * 32;
      uint4 u00 = *(const uint4*)(xb + i00 + cb);
      uint4 u01 = *(const uint4*)(xb + i01 + cb);
      uint4 u10 = *(const uint4*)(xb + i10 + cb);
      uint4 u11 = *(const uint4*)(xb + i11 + cb);
      uint4 ap;
      ap.x = bilin_pack(u00.x, u01.x, u10.x, u11.x, C00, C01, C10, C11);
      ap.y = bilin_pack(u00.y, u01.y, u10.y, u11.y, C00, C01, C10, C11);
      ap.z = bilin_pack(u00.z, u01.z, u10.z, u11.z, C00, C01, C10, C11);
      ap.w = bilin_pack(u00.w, u01.w, u10.w, u11.w, C00, C01, C10, C11);
      short8 a = *(short8*)&ap;
      const ushort* fbase = wdts + (size_t)((ts * 2 + half) * 4) * 512 + l * 8;
#pragma unroll
      for (int j = 0; j < 4; ++j) {
        short8 bf = *(const short8*)(fbase + j * 512);
        acc[j] = __builtin_amdgcn_mfma_f32_16x16x32_bf16(a, bf, acc[j], 0, 0, 0);
      }
    }
  }

  __syncthreads();   // all s_cv reads done before s_red overwrites the union
  // K-split reduction across the 4 waves. D map: col=lm(co), row=lk*4+r(pixel).
#pragma unroll
  for (int j = 0; j < 4; ++j)
#pragma unroll
    for (int r = 0; r < 4; ++r)
      s_red[w][lk * 4 + r][j * 16 + lm] = acc[j][r];
  __syncthreads();
  int rem0 = m0 - b * HW;
#pragma unroll
  for (int i = 0; i < 4; ++i) {
    int idx = i * 256 + tid;
    int mrow = idx & 15, co = idx >> 4;
    float v = s_red[0][mrow][co] + s_red[1][mrow][co] +
              s_red[2][mrow][co] + s_red[3][mrow][co];
    out[(size_t)(b * (3 * COUT) + br_off + co) * HW + rem0 + mrow] = v;
  }
}

__global__ __launch_bounds__(256, 8) void dcn_all(
    const ushort* __restrict__ xhb,
    const float* __restrict__ co7, const ushort* __restrict__ wdts7,
    const float* __restrict__ co5, const ushort* __restrict__ wdts5,
    const float* __restrict__ co3, const ushort* __restrict__ wdts3,
    float* __restrict__ out) {
  __shared__ float smem[4 * 16 * 65];   // union: s_cv (<=2352) / s_red (4160)
  int blk = blockIdx.x;
  if (blk < 800) dcn_body<7>(blk, xhb, co7, wdts7, out, 128, smem);
  else if (blk < 1600) dcn_body<5>(blk - 800, xhb, co5, wdts5, out, 64, smem);
  else dcn_body<3>(blk - 1600, xhb, co3, wdts3, out, 0, smem);
}

// ---------------------------------------------------------------------------
// Launch
// ---------------------------------------------------------------------------
extern "C" void kernel_launch(void* const* d_in, const int* in_sizes, int n_in,
                              void* d_out, int out_size, void* d_ws,
                              size_t ws_size, hipStream_t stream) {
  const float* x = (const float*)d_in[0];
  const float* w_off3 = (const float*)d_in[1];
  const float* b_off3 = (const float*)d_in[2];
  const float* w_mask3 = (const float*)d_in[3];
  const float* b_mask3 = (const float*)d_in[4];
  const float* w_dcn3 = (const float*)d_in[5];
  const float* w_off5 = (const float*)d_in[6];
  const float* b_off5 = (const float*)d_in[7];
  const float* w_mask5 = (const float*)d_in[8];
  const float* b_mask5 = (const float*)d_in[9];
  const float* w_dcn5 = (const float*)d_in[10];
  const float* w_off7 = (const float*)d_in[11];
  const float* b_off7 = (const float*)d_in[12];
  const float* w_mask7 = (const float*)d_in[13];
  const float* b_mask7 = (const float*)d_in[14];
  const float* w_dcn7 = (const float*)d_in[15];
  float* out = (float*)d_out;
  float* ws = (float*)d_ws;

  // Workspace layout (float units, 16B aligned)
  size_t off = 0;
  auto alloc = [&](size_t n) {
    size_t p = off;
    off += (n + 3) & ~(size_t)3;
    return ws + p;
  };
  ushort* xhb = (ushort*)alloc((size_t)NPIX * C / 2 + 64);  // +zero row
  float* co3 = alloc((size_t)NPIX * 27);
  float* co5 = alloc((size_t)NPIX * 75);
  float* co7 = alloc((size_t)NPIX * 147);
  ushort* wtbs3 = (ushort*)alloc(9 * 2 * 2 * 512 / 2);
  ushort* wtbs5 = (ushort*)alloc(25 * 2 * 6 * 512 / 2);
  ushort* wtbs7 = (ushort*)alloc(49 * 2 * 10 * 512 / 2);
  float* bc3 = alloc(27);
  float* bc5 = alloc(75);
  float* bc7 = alloc(147);
  ushort* wdts3 = (ushort*)alloc(9 * 2 * 4 * 512 / 2);
  ushort* wdts5 = (ushort*)alloc(25 * 2 * 4 * 512 / 2);
  ushort* wdts7 = (ushort*)alloc(49 * 2 * 4 * 512 / 2);

  // 1) transpose + all weight prep (one launch)
  setup_all<<<456, 256, 0, stream>>>(
      x, xhb,
      w_off3, b_off3, w_mask3, b_mask3, w_dcn3, wtbs3, bc3, wdts3,
      w_off5, b_off5, w_mask5, b_mask5, w_dcn5, wtbs5, bc5, wdts5,
      w_off7, b_off7, w_mask7, b_mask7, w_dcn7, wtbs7, bc7, wdts7);

  // 2) all offset+mask convs (one launch; k=7 1000 blocks, k=5 400, k=3 200)
  conv_all<<<1600, 256, 0, stream>>>(xhb, wtbs7, bc7, co7, wtbs5, bc5, co5,
                                     wtbs3, bc3, co3);

  // 3) all fused deformable sampling + einsum (one launch, k=7 first)
  dcn_all<<<2400, 256, 0, stream>>>(xhb, co7, wdts7, co5, wdts5, co3, wdts3,
                                    out);
}